// Round 5
// baseline (604.214 us; speedup 1.0000x reference)
//
#include <hip/hip_runtime.h>
#include <hip/hip_bf16.h>

#define IN_DIM 128
#define HID    64
#define OUTD   64
#define NPART  8

typedef __attribute__((ext_vector_type(8))) short bf16x8;
typedef __attribute__((ext_vector_type(4))) float f32x4;

__device__ __forceinline__ float gelu_exact(float v) {
    return v * 0.5f * (1.0f + erff(v * 0.70710678118654752f));
}
__device__ __forceinline__ short f2bf(float f) {
    __hip_bfloat16 b = __float2bfloat16(f);   // RNE
    return *reinterpret_cast<short*>(&b);
}
__device__ __forceinline__ float bf2f(ushort u) {
    return __uint_as_float(((unsigned)u) << 16);
}

#define WREDUCE(v) { v += __shfl_xor(v,32,64); v += __shfl_xor(v,16,64); \
                     v += __shfl_xor(v,8,64);  v += __shfl_xor(v,4,64);  \
                     v += __shfl_xor(v,2,64);  v += __shfl_xor(v,1,64); }

// ---------------------------------------------------------------------------
// K1: node projection via MFMA bf16 (unchanged; not the bottleneck).
// ---------------------------------------------------------------------------
__global__ __launch_bounds__(256) void gat_node_proj_mfma(
    const float* __restrict__ x, const float* __restrict__ w_in,
    const float* __restrict__ b_in, const float* __restrict__ w,
    const float* __restrict__ a,
    ushort* __restrict__ zb, float* __restrict__ s1, float* __restrict__ s2,
    int n_nodes, int ntiles)
{
    __shared__ ushort h0s[4][16 * 64];

    const int tid = threadIdx.x;
    const int wv = tid >> 6, l = tid & 63;
    const int c = l & 15, g = l >> 4;

    bf16x8 B1[4][4];
    #pragma unroll
    for (int s = 0; s < 4; ++s)
        #pragma unroll
        for (int t = 0; t < 4; ++t) {
            bf16x8 f;
            #pragma unroll
            for (int e = 0; e < 8; ++e)
                f[e] = f2bf(w_in[(s * 32 + g * 8 + e) * HID + t * 16 + c]);
            B1[s][t] = f;
        }
    bf16x8 B2[2][4];
    #pragma unroll
    for (int s = 0; s < 2; ++s)
        #pragma unroll
        for (int t = 0; t < 4; ++t) {
            bf16x8 f;
            #pragma unroll
            for (int e = 0; e < 8; ++e)
                f[e] = f2bf(w[(s * 32 + g * 8 + e) * OUTD + t * 16 + c]);
            B2[s][t] = f;
        }
    float bias[4], a1c[4], a2c[4];
    #pragma unroll
    for (int t = 0; t < 4; ++t) {
        bias[t] = b_in[t * 16 + c];
        a1c[t]  = a[t * 16 + c];
        a2c[t]  = a[OUTD + t * 16 + c];
    }

    ushort* hrow = &h0s[wv][0];

    for (int tile = blockIdx.x; tile < ntiles; tile += gridDim.x) {
        const int nbase = tile * 64 + wv * 16;

        const int row = min(nbase + c, n_nodes - 1);
        const float* xp = x + (size_t)row * IN_DIM;
        bf16x8 A1[4];
        #pragma unroll
        for (int s = 0; s < 4; ++s) {
            const float4 u0 = *(const float4*)(xp + s * 32 + g * 8);
            const float4 u1 = *(const float4*)(xp + s * 32 + g * 8 + 4);
            bf16x8 f;
            f[0] = f2bf(u0.x); f[1] = f2bf(u0.y); f[2] = f2bf(u0.z); f[3] = f2bf(u0.w);
            f[4] = f2bf(u1.x); f[5] = f2bf(u1.y); f[6] = f2bf(u1.z); f[7] = f2bf(u1.w);
            A1[s] = f;
        }

        #pragma unroll
        for (int t = 0; t < 4; ++t) {
            f32x4 acc = {0.f, 0.f, 0.f, 0.f};
            #pragma unroll
            for (int s = 0; s < 4; ++s)
                acc = __builtin_amdgcn_mfma_f32_16x16x32_bf16(A1[s], B1[s][t], acc, 0, 0, 0);
            #pragma unroll
            for (int r = 0; r < 4; ++r) {
                const int m = g * 4 + r;
                const int n = t * 16 + c;
                const float h0 = gelu_exact(acc[r] + bias[t]);
                hrow[m * 64 + (n ^ ((m & 7) << 3))] = (ushort)f2bf(h0);
            }
        }
        __syncthreads();

        bf16x8 A2[2];
        #pragma unroll
        for (int s = 0; s < 2; ++s) {
            const int k = s * 32 + g * 8;
            A2[s] = *(const bf16x8*)(hrow + c * 64 + (k ^ ((c & 7) << 3)));
        }

        f32x4 C2[4];
        #pragma unroll
        for (int t = 0; t < 4; ++t) {
            f32x4 acc = {0.f, 0.f, 0.f, 0.f};
            acc = __builtin_amdgcn_mfma_f32_16x16x32_bf16(A2[0], B2[0][t], acc, 0, 0, 0);
            acc = __builtin_amdgcn_mfma_f32_16x16x32_bf16(A2[1], B2[1][t], acc, 0, 0, 0);
            C2[t] = acc;
        }

        float p1v[4] = {0.f, 0.f, 0.f, 0.f}, p2v[4] = {0.f, 0.f, 0.f, 0.f};
        #pragma unroll
        for (int t = 0; t < 4; ++t)
            #pragma unroll
            for (int r = 0; r < 4; ++r) {
                p1v[r] = fmaf(C2[t][r], a1c[t], p1v[r]);
                p2v[r] = fmaf(C2[t][r], a2c[t], p2v[r]);
                const int node = nbase + g * 4 + r;
                if (node < n_nodes)
                    zb[(size_t)node * OUTD + t * 16 + c] = (ushort)f2bf(C2[t][r]);
            }

        #pragma unroll
        for (int r = 0; r < 4; ++r) {
            p1v[r] += __shfl_xor(p1v[r], 1, 64);
            p1v[r] += __shfl_xor(p1v[r], 2, 64);
            p1v[r] += __shfl_xor(p1v[r], 4, 64);
            p1v[r] += __shfl_xor(p1v[r], 8, 64);
            p2v[r] += __shfl_xor(p2v[r], 1, 64);
            p2v[r] += __shfl_xor(p2v[r], 2, 64);
            p2v[r] += __shfl_xor(p2v[r], 4, 64);
            p2v[r] += __shfl_xor(p2v[r], 8, 64);
        }
        const float v1 = (c == 0) ? p1v[0] : (c == 1) ? p1v[1] : (c == 2) ? p1v[2] : p1v[3];
        const float v2 = (c == 0) ? p2v[0] : (c == 1) ? p2v[1] : (c == 2) ? p2v[2] : p2v[3];
        const int snode = nbase + g * 4 + c;
        if (c < 4 && snode < n_nodes) { s1[snode] = v1; s2[snode] = v2; }
        __syncthreads();
    }
}

// ---------------------------------------------------------------------------
// CSR build v2: single-read 8-way bucket partition.
//   count8: per-partition edge counts (one read of dst)
//   off8:   exclusive prefix (1 thread)
//   bucket: LDS-staged append of packed (dst_local<<17 | src) per partition
//           (sequential coalesced bucket writes; edges read ONCE)
//   hist_b / scatter_b: per-partition (blockIdx&7 -> XCD-matched), all
//           deg/cursor atomics + csr writes land in one XCD's L2.
// Pack requires n_nodes <= 131072 (17b src) and part_sz <= 16384 (14b local).
// ---------------------------------------------------------------------------
__global__ __launch_bounds__(256) void k_count8(
    const int* __restrict__ dst, int* __restrict__ cnt8, int n_edges, int part_sz)
{
    __shared__ int c[NPART];
    if (threadIdx.x < NPART) c[threadIdx.x] = 0;
    __syncthreads();
    for (int e = blockIdx.x * 256 + threadIdx.x; e < n_edges; e += gridDim.x * 256)
        atomicAdd(&c[dst[e] / part_sz], 1);
    __syncthreads();
    if (threadIdx.x < NPART) atomicAdd(&cnt8[threadIdx.x], c[threadIdx.x]);
}

__global__ void k_off8(const int* __restrict__ cnt8, int* __restrict__ off8)
{
    if (threadIdx.x == 0) {
        int a = 0;
        for (int p = 0; p < NPART; ++p) { off8[p] = a; a += cnt8[p]; }
        off8[NPART] = a;
    }
}

__global__ __launch_bounds__(256) void k_bucket(
    const int* __restrict__ src, const int* __restrict__ dst,
    const int* __restrict__ off8, int* __restrict__ tail8,
    unsigned* __restrict__ bkt, int n_edges, int part_sz)
{
    // capacity 384 = worst-case remainder(<128) + one full tile(256): absolute-safe
    __shared__ unsigned buf[NPART][384];
    __shared__ int cnt[NPART];
    const int tid = threadIdx.x;
    const int wv = tid >> 6, lane = tid & 63;
    if (tid < NPART) cnt[tid] = 0;
    __syncthreads();

    const int tiles = (n_edges + 255) >> 8;
    for (int t = blockIdx.x; t < tiles; t += gridDim.x) {
        const int e = (t << 8) + tid;
        if (e < n_edges) {
            const int d = dst[e];
            const int s = src[e];
            const int p = d / part_sz;
            const unsigned pk = ((unsigned)(d - p * part_sz) << 17) | (unsigned)s;
            const int pos = atomicAdd(&cnt[p], 1);
            buf[p][pos] = pk;
        }
        __syncthreads();
        #pragma unroll
        for (int pp = wv; pp < NPART; pp += 4) {
            const int k = cnt[pp];
            if (k >= 128) {
                int base = 0;
                if (lane == 0) base = atomicAdd(&tail8[pp], k);
                base = __shfl(base, 0, 64);
                const int go = off8[pp] + base;
                for (int i = lane; i < k; i += 64) bkt[go + i] = buf[pp][i];
                if (lane == 0) cnt[pp] = 0;
            }
        }
        __syncthreads();
    }
    #pragma unroll
    for (int pp = wv; pp < NPART; pp += 4) {
        const int k = cnt[pp];
        if (k > 0) {
            int base = 0;
            if (lane == 0) base = atomicAdd(&tail8[pp], k);
            base = __shfl(base, 0, 64);
            const int go = off8[pp] + base;
            for (int i = lane; i < k; i += 64) bkt[go + i] = buf[pp][i];
        }
    }
}

__global__ __launch_bounds__(256) void k_hist_b(
    const unsigned* __restrict__ bkt, const int* __restrict__ cnt8,
    const int* __restrict__ off8, int* __restrict__ deg, int part_sz)
{
    const int p = blockIdx.x & (NPART - 1);
    const int n = cnt8[p];
    const unsigned* b = bkt + off8[p];
    const int lo = p * part_sz;
    const int stride = (gridDim.x >> 3) * 256;
    for (int i = (blockIdx.x >> 3) * 256 + threadIdx.x; i < n; i += stride)
        atomicAdd(&deg[lo + (int)(b[i] >> 17)], 1);
}

__global__ __launch_bounds__(256) void k_scatter_b(
    const unsigned* __restrict__ bkt, const int* __restrict__ cnt8,
    const int* __restrict__ off8, int* __restrict__ cursor,
    int* __restrict__ csr, int part_sz)
{
    const int p = blockIdx.x & (NPART - 1);
    const int n = cnt8[p];
    const unsigned* b = bkt + off8[p];
    const int lo = p * part_sz;
    const int stride = (gridDim.x >> 3) * 256;
    for (int i = (blockIdx.x >> 3) * 256 + threadIdx.x; i < n; i += stride) {
        const unsigned v = b[i];
        const int d = lo + (int)(v >> 17);
        const int pos = atomicAdd(&cursor[d], 1);
        csr[pos] = (int)(v & 0x1FFFFu);
    }
}

__global__ __launch_bounds__(1024) void k_scan_block(
    const int* __restrict__ deg, int* __restrict__ rs,
    int* __restrict__ bsum, int n)
{
    __shared__ int buf[1024];
    const int tid = threadIdx.x;
    const int gid = blockIdx.x * 1024 + tid;
    const int v = (gid < n) ? deg[gid] : 0;
    buf[tid] = v;
    __syncthreads();
    #pragma unroll
    for (int off = 1; off < 1024; off <<= 1) {
        int t = (tid >= off) ? buf[tid - off] : 0;
        __syncthreads();
        buf[tid] += t;
        __syncthreads();
    }
    if (gid < n) rs[gid] = buf[tid] - v;
    if (tid == 1023) bsum[blockIdx.x] = buf[1023];
}

__global__ __launch_bounds__(128) void k_scan_bsum(int* __restrict__ bsum, int nb)
{
    __shared__ int buf[128];
    const int tid = threadIdx.x;
    const int v = (tid < nb) ? bsum[tid] : 0;
    buf[tid] = v;
    __syncthreads();
    #pragma unroll
    for (int off = 1; off < 128; off <<= 1) {
        int t = (tid >= off) ? buf[tid - off] : 0;
        __syncthreads();
        buf[tid] += t;
        __syncthreads();
    }
    if (tid < nb) bsum[tid] = buf[tid] - v;
}

__global__ __launch_bounds__(1024) void k_add_off(
    int* __restrict__ rs, int* __restrict__ cursor,
    const int* __restrict__ bsum, int n)
{
    const int gid = blockIdx.x * 1024 + threadIdx.x;
    if (gid < n) {
        const int v = rs[gid] + bsum[blockIdx.x];
        rs[gid] = v;
        cursor[gid] = v;
    }
}

// ---------------------------------------------------------------------------
// K_agg: wave per dst node. Unroll-4 over edges: 4 independent z-gathers in
// flight per wave (4x MLP vs R4's serial loop). Padding lanes carry exv=0,
// sidx=0 -> fma no-ops, row-0 loads harmless.
// ---------------------------------------------------------------------------
__global__ __launch_bounds__(256) void gat_agg(
    const int* __restrict__ rs, const int* __restrict__ deg,
    const int* __restrict__ csr,
    const float* __restrict__ s1, const float* __restrict__ s2,
    const ushort* __restrict__ zb, float* __restrict__ h, int n_nodes)
{
    const int wv = threadIdx.x >> 6, lane = threadIdx.x & 63;
    const int node = blockIdx.x * 4 + wv;
    if (node >= n_nodes) return;

    const int base = rs[node];
    const int cnt = deg[node];
    const float s2d = s2[node];

    float acc = 0.f, den = 0.f;
    for (int c0 = 0; c0 < cnt; c0 += 64) {
        const int m = min(64, cnt - c0);
        int sidx = 0;
        float exv = 0.f;
        if (lane < m) {
            sidx = csr[base + c0 + lane];
            float e = s1[sidx] + s2d;
            e = e > 0.f ? e : 0.01f * e;
            exv = __expf(e);
        }
        float dsum = exv;
        WREDUCE(dsum);
        den += dsum;

        const int mr = (m + 3) & ~3;
        for (int j = 0; j < mr; j += 4) {
            const int   i0 = __shfl(sidx, j,     64);
            const int   i1 = __shfl(sidx, j + 1, 64);
            const int   i2 = __shfl(sidx, j + 2, 64);
            const int   i3 = __shfl(sidx, j + 3, 64);
            const float e0 = __shfl(exv,  j,     64);
            const float e1 = __shfl(exv,  j + 1, 64);
            const float e2 = __shfl(exv,  j + 2, 64);
            const float e3 = __shfl(exv,  j + 3, 64);
            const float v0 = bf2f(zb[(size_t)i0 * OUTD + lane]);
            const float v1 = bf2f(zb[(size_t)i1 * OUTD + lane]);
            const float v2 = bf2f(zb[(size_t)i2 * OUTD + lane]);
            const float v3 = bf2f(zb[(size_t)i3 * OUTD + lane]);
            acc = fmaf(e0, v0, acc);
            acc = fmaf(e1, v1, acc);
            acc = fmaf(e2, v2, acc);
            acc = fmaf(e3, v3, acc);
        }
    }
    h[(size_t)node * OUTD + lane] = acc / fmaxf(den, 1e-9f);
}

extern "C" void kernel_launch(void* const* d_in, const int* in_sizes, int n_in,
                              void* d_out, int out_size, void* d_ws, size_t ws_size,
                              hipStream_t stream)
{
    const float* x    = (const float*)d_in[0];
    const float* w_in = (const float*)d_in[1];
    const float* b_in = (const float*)d_in[2];
    const float* w    = (const float*)d_in[3];
    const float* a    = (const float*)d_in[4];
    const int*   src  = (const int*)d_in[5];
    const int*   dst  = (const int*)d_in[6];
    const int n_nodes = in_sizes[0] / IN_DIM;
    const int n_edges = in_sizes[5];

    float* h = (float*)d_out;

    // workspace layout (~28 MB)
    ushort*   zb     = (ushort*)d_ws;                        // n_nodes*64 bf16
    float*    s1     = (float*)(zb + (size_t)n_nodes * OUTD);
    float*    s2     = s1 + n_nodes;
    int*      deg    = (int*)(s2 + n_nodes);                 // n_nodes
    int*      cnt8   = deg + n_nodes;                        // 8
    int*      tail8  = cnt8 + NPART;                         // 8
    int*      off8   = tail8 + NPART;                        // 9 (+pad to 64)
    int*      rs     = deg + n_nodes + 64;                   // n_nodes
    int*      cursor = rs + n_nodes;                         // n_nodes
    int*      bsum   = cursor + n_nodes;                     // 128
    int*      csr    = bsum + 128;                           // n_edges
    unsigned* bkt    = (unsigned*)(csr + n_edges);           // n_edges

    const int nb = (n_nodes + 1023) / 1024;
    const int ntiles = (n_nodes + 63) / 64;
    const int part_sz = (n_nodes + NPART - 1) / NPART;

    // zero deg + cnt8 + tail8 (+pad) in one memset
    hipMemsetAsync(deg, 0, (size_t)(n_nodes + 64) * sizeof(int), stream);

    k_count8<<<2048, 256, 0, stream>>>(dst, cnt8, n_edges, part_sz);
    k_off8<<<1, 64, 0, stream>>>(cnt8, off8);
    k_bucket<<<2048, 256, 0, stream>>>(src, dst, off8, tail8, bkt, n_edges, part_sz);
    k_hist_b<<<2048, 256, 0, stream>>>(bkt, cnt8, off8, deg, part_sz);
    k_scan_block<<<nb, 1024, 0, stream>>>(deg, rs, bsum, n_nodes);
    k_scan_bsum<<<1, 128, 0, stream>>>(bsum, nb);
    k_add_off<<<nb, 1024, 0, stream>>>(rs, cursor, bsum, n_nodes);
    k_scatter_b<<<2048, 256, 0, stream>>>(bkt, cnt8, off8, cursor, csr, part_sz);

    gat_node_proj_mfma<<<523, 256, 0, stream>>>(x, w_in, b_in, w, a,
                                                zb, s1, s2, n_nodes, ntiles);

    gat_agg<<<(n_nodes + 3) / 4, 256, 0, stream>>>(rs, deg, csr, s1, s2, zb, h, n_nodes);
}